// Round 15
// baseline (433.153 us; speedup 1.0000x reference)
//
#include <hip/hip_runtime.h>
#include <cstdint>
#include <cstddef>

// ---------------------------------------------------------------------------
// TemporalGNN: 2x EvolveGCNH (TopK-pool -> GRU weight evolve -> GCNConv) + MLP
// N=100000 nodes, F=128, E=625000 edges, all fp32.
// R15: NT hints reverted (R14 regression). gather+GEMM fused per layer
//      (k_fgg): wave gathers 16 node rows -> LDS [16][132] -> MFMA vs W
//      -> fused epilogue. Kills g1 (51+51MB) and g2 (25+25MB) round-trips;
//      layer-1 score/collect returns as standalone pass (+51MB).
// ---------------------------------------------------------------------------

#define FDIM 128

typedef __attribute__((ext_vector_type(8))) short bfrag;   // 8 bf16 (4 VGPRs)
typedef __attribute__((ext_vector_type(4))) float f32x4;
typedef __attribute__((ext_vector_type(2))) float f32x2;

__device__ __forceinline__ float wave_sum(float v) {
#pragma unroll
  for (int m = 32; m >= 1; m >>= 1) v += __shfl_xor(v, m, 64);
  return v;
}

__device__ __forceinline__ float sigmoidf_(float x) {
  return 1.0f / (1.0f + expf(-x));
}

// monotone float->uint map (order-preserving)
__device__ __forceinline__ unsigned omap(float f) {
  unsigned u = __float_as_uint(f);
  return (u & 0x80000000u) ? ~u : (u | 0x80000000u);
}

// xcd-chunked block remap (requires gridDim.x % 8 == 0)
__device__ __forceinline__ int xcd_chunk(int b, int nb) {
  return (b & 7) * (nb >> 3) + (b >> 3);
}

// ---------------- setup: degree, CSR build -----------------------------------

__global__ void k_edge_deg(const int* __restrict__ ei, const float* __restrict__ ew,
                           float* deg, int* cnt, int E) {
  int e = blockIdx.x * blockDim.x + threadIdx.x;
  if (e < E) {
    int c = ei[E + e];                         // col
    atomicAdd(&deg[c], ew[e]);
    atomicAdd(&cnt[c], 1);
  }
}

// block sums for cnt (1024/block) + dinv = rsqrt(1 + sum(w)) (self-loop)
__global__ void k_scan1(const int* __restrict__ cnt, int* bsum,
                        const float* __restrict__ deg, float* __restrict__ dinv, int n) {
  __shared__ int s[256];
  int b = blockIdx.x, t = threadIdx.x;
  int base = b * 1024;
  int v = 0;
#pragma unroll
  for (int j = 0; j < 4; j++) {
    int i = base + j * 256 + t;
    if (i < n) { v += cnt[i]; dinv[i] = 1.0f / sqrtf(1.0f + deg[i]); }
  }
  s[t] = v; __syncthreads();
  for (int off = 128; off > 0; off >>= 1) { if (t < off) s[t] += s[t + off]; __syncthreads(); }
  if (t == 0) bsum[b] = s[0];
}

// exclusive scan of bsum in LDS + rstart[N]=E + tiny per-layer setup (merged)
__global__ __launch_bounds__(128) void k_scan2_setup(
    int* bsum, int nb, int* rstartN,
    const float* p1, const float* p2, float* invn1, float* invn2,
    const float* l1w, const float* l1b, const float* l2w, const float* l2b,
    float* v, float* cc) {
  __shared__ int s[1024];
  int t = threadIdx.x;
  for (int i = t; i < nb; i += 128) s[i] = bsum[i];
  __syncthreads();
  if (t == 0) {
    int run = 0;
    for (int b = 0; b < nb; b++) { int x = s[b]; s[b] = run; run += x; }
    s[1023] = run;
  }
  __syncthreads();
  for (int i = t; i < nb; i += 128) bsum[i] = s[i];
  if (t == 0) rstartN[0] = s[1023];
  int wv = t >> 6, l = t & 63;
  const float* p = wv ? p2 : p1;
  float2 pv = ((const float2*)p)[l];
  float ss = wave_sum(pv.x * pv.x + pv.y * pv.y);
  if (l == 0) (wv ? invn2 : invn1)[0] = 1.0f / sqrtf(ss);
  v[t] = l2w[0] * l1w[t] + l2w[1] * l1w[128 + t];
  if (t == 0) cc[0] = l2w[0] * l1b[0] + l2w[1] * l1b[1] + l2b[0];
}

__global__ __launch_bounds__(1024) void k_scan3(const int* __restrict__ cnt,
                                                const int* __restrict__ bsum,
                                                int* rstart, int* rnext, int n) {
  __shared__ int s[1024];
  int b = blockIdx.x, t = threadIdx.x;
  int i = b * 1024 + t;
  int v = (i < n) ? cnt[i] : 0;
  s[t] = v; __syncthreads();
  for (int off = 1; off < 1024; off <<= 1) {
    int tmp = (t >= off) ? s[t - off] : 0;
    __syncthreads();
    s[t] += tmp;
    __syncthreads();
  }
  if (i < n) { int ex = bsum[b] + s[t] - v; rstart[i] = ex; rnext[i] = ex; }
}

// scatter edge payload (row, norm) into CSR slots
__global__ void k_fill(const int* __restrict__ ei, const float* __restrict__ ew,
                       const float* __restrict__ dinv, int* rnext, int2* pay, int E) {
  int e = blockIdx.x * blockDim.x + threadIdx.x;
  if (e < E) {
    int r = ei[e];
    int c = ei[E + e];
    float nm = dinv[r] * ew[e] * dinv[c];
    int pos = atomicAdd(&rnext[c], 1);
    pay[pos] = make_int2(r, __float_as_int(nm));
  }
}

// ---------------- top-k helpers ----------------------------------------------

__global__ void k_sampdots(const float* __restrict__ x, const float* __restrict__ p,
                           const float* __restrict__ invn, float* __restrict__ samp,
                           int stride) {
  int l = threadIdx.x & 63;
  int w = blockIdx.x * 4 + (threadIdx.x >> 6);   // 0..511
  float2 pv = ((const float2*)p)[l];
  float inv = invn[0];
#pragma unroll
  for (int r = 0; r < 4; r++) {
    int si = w * 4 + r;
    float2 a = ((const float2*)(x + (size_t)(si * stride) * FDIM))[l];
    float s = wave_sum(a.x * pv.x + a.y * pv.y) * inv;
    if (l == 0) samp[si] = s;
  }
}

// 16th largest of 2048: 32 blocks, 4 lanes/candidate, shfl-combined rank count
template <int STRIDED>
__global__ __launch_bounds__(256) void k_thr16(const float* __restrict__ src, int stride,
                                               float* __restrict__ thr) {
  __shared__ float a[2048];
  int t = threadIdx.x;
  for (int i = t; i < 2048; i += 256)
    a[i] = STRIDED ? src[(size_t)i * stride] : src[i];
  __syncthreads();
  int g = blockIdx.x * 256 + t;        // 0..8191
  int j = g >> 2, sub = g & 3;         // candidate, quarter
  float v = a[j];
  int gt = 0, eq = 0;
  const float4* a4 = (const float4*)(a + sub * 512);
#pragma unroll 8
  for (int i = 0; i < 128; i++) {
    float4 b = a4[i];
    gt += (b.x > v) + (b.y > v) + (b.z > v) + (b.w > v);
    eq += (b.x == v) + (b.y == v) + (b.z == v) + (b.w == v);
  }
  gt += __shfl_xor(gt, 1, 64); eq += __shfl_xor(eq, 1, 64);
  gt += __shfl_xor(gt, 2, 64); eq += __shfl_xor(eq, 2, 64);
  if (sub == 0 && gt <= 15 && gt + eq > 15) thr[0] = v;
}

// score all rows, collect >= thr directly
__global__ void k_scorecollect(const float* __restrict__ x, const float* __restrict__ p,
                               const float* __restrict__ invn, const float* __restrict__ thr,
                               unsigned long long* __restrict__ candk, int* __restrict__ csel,
                               int n) {
  int l = threadIdx.x & 63;
  int eb = xcd_chunk(blockIdx.x, gridDim.x);
  int base = (eb * 4 + (threadIdx.x >> 6)) * 16;
  if (base >= n) return;
  float2 pv = ((const float2*)p)[l];
  float inv = invn[0], th = thr[0];
  int lim = min(16, n - base);
  for (int r = 0; r < lim; r++) {
    float2 a = ((const float2*)(x + (size_t)(base + r) * FDIM))[l];
    float s = wave_sum(a.x * pv.x + a.y * pv.y) * inv;
    if (l == 0 && s >= th) {
      int pos = atomicAdd(csel, 1);
      if (pos < 4096)
        candk[pos] = ((unsigned long long)omap(s) << 32) | (unsigned)(~(unsigned)(base + r));
    }
  }
}

__global__ void k_collect(const float* __restrict__ sc, const float* __restrict__ thr,
                          unsigned long long* candk, int* csel, int n) {
  int i = blockIdx.x * blockDim.x + threadIdx.x;
  if (i >= n) return;
  float s = sc[i];
  if (s >= thr[0]) {
    int pos = atomicAdd(csel, 1);
    if (pos < 4096)
      candk[pos] = ((unsigned long long)omap(s) << 32) | (unsigned)(~(unsigned)i);
  }
}

// exact top-128 via rank counting (keys unique; 0ULL pads rank-neutral)
__global__ __launch_bounds__(1024) void k_sel(const unsigned long long* __restrict__ candk,
                                              const int* __restrict__ csel,
                                              int* tidx, float* ttanh) {
  __shared__ unsigned long long a[4104];
  int t = threadIdx.x;
  int nc = csel[0]; if (nc > 4096) nc = 4096;
  int ncp = (nc + 7) & ~7;
  for (int i = t; i < ncp; i += 1024) a[i] = (i < nc) ? candk[i] : 0ULL;
  __syncthreads();
  for (int j = t; j < nc; j += 1024) {
    unsigned long long key = a[j];
    int r = 0;
#pragma unroll 8
    for (int i = 0; i < ncp; i++) r += (a[i] > key);
    if (r < 128) {
      unsigned idx = ~(unsigned)key;
      unsigned hi = (unsigned)(key >> 32);
      unsigned u = (hi & 0x80000000u) ? (hi ^ 0x80000000u) : ~hi;
      tidx[r] = (int)idx;
      ttanh[r] = tanhf(__uint_as_float(u));
    }
  }
}

// ---------------- GRU weight evolve -> bf16-split transposed weights --------
// BF16IN=1: xin is bf16 (h1).

template <int BF16IN>
__global__ __launch_bounds__(384) void k_gru(const void* __restrict__ xinv,
                                             const int* __restrict__ tidx,
                                             const float* __restrict__ ttanh,
                                             const float* __restrict__ wih,
                                             const float* __restrict__ whh,
                                             const float* __restrict__ bih,
                                             const float* __restrict__ bhh,
                                             const float* __restrict__ h0,
                                             unsigned short* __restrict__ WT_hi,
                                             unsigned short* __restrict__ WT_lo) {
  __shared__ float xt[128], hs[128], gis[384], ghs[384];
  int r = blockIdx.x, t = threadIdx.x;
  if (t < 128) {
    int idx = tidx[r];
    float xv;
    if (BF16IN) {
      unsigned short u = ((const unsigned short*)xinv)[(size_t)idx * FDIM + t];
      xv = __uint_as_float((unsigned)u << 16);
    } else {
      xv = ((const float*)xinv)[(size_t)idx * FDIM + t];
    }
    xt[t] = xv * ttanh[r];
    hs[t] = h0[r * FDIM + t];
  }
  __syncthreads();
  float gi = bih[t], gh = bhh[t];
  const float4* wi4 = (const float4*)(wih + (size_t)t * FDIM);
  const float4* wh4 = (const float4*)(whh + (size_t)t * FDIM);
#pragma unroll 8
  for (int k = 0; k < 32; k++) {
    float4 av = wi4[k], bv = wh4[k];
    gi += av.x * xt[4 * k] + av.y * xt[4 * k + 1] + av.z * xt[4 * k + 2] + av.w * xt[4 * k + 3];
    gh += bv.x * hs[4 * k] + bv.y * hs[4 * k + 1] + bv.z * hs[4 * k + 2] + bv.w * hs[4 * k + 3];
  }
  gis[t] = gi; ghs[t] = gh;
  __syncthreads();
  if (t < 128) {
    float rg = sigmoidf_(gis[t] + ghs[t]);
    float zg = sigmoidf_(gis[t + 128] + ghs[t + 128]);
    float ng = tanhf(gis[t + 256] + rg * ghs[t + 256]);
    float w = (1.0f - zg) * ng + zg * hs[t];
    unsigned u = __float_as_uint(w);
    float res = w - __uint_as_float(u & 0xFFFF0000u);
    WT_hi[t * FDIM + r] = (unsigned short)(u >> 16);
    WT_lo[t * FDIM + r] = (unsigned short)(__float_as_uint(res) >> 16);
  }
}

// ---------------- fused gather + GEMM + epilogue -----------------------------
// Per wave: gather 16 node rows (8-deep asm-pipelined edge loads) into LDS
// [16][132] (conflict-free frag read-back), then MFMA vs W (B frags from L2,
// 64KB hot) with fused epilogue.
// MODE=1: in = x fp32 (512B rows); A fp32 3-pass; out h1 bf16 + sc2.
// MODE=2: in = h1 bf16 (256B rows); A quantized bf16 2-pass; out = head.

template <int MODE>
__global__ __launch_bounds__(256) void k_fgg(const void* __restrict__ inv,
                                             const unsigned short* __restrict__ BTh,
                                             const unsigned short* __restrict__ BTl,
                                             const float* __restrict__ dinv,
                                             const int* __restrict__ rstart,   // N+1
                                             const int2* __restrict__ pay,
                                             unsigned short* __restrict__ Y2,
                                             float* __restrict__ scOut,
                                             const float* __restrict__ pvec,
                                             const float* __restrict__ scal,
                                             int n) {
  __shared__ float gst[4][16][132];
  int tid = threadIdx.x;
  int wv = tid >> 6, l = tid & 63;
  int eb = xcd_chunk(blockIdx.x, gridDim.x);
  int base = eb * 64 + wv * 16;

  // ---- phase A: gather 16 rows into LDS ----
  for (int i = 0; i < 16; i++) {
    int c = base + i;
    float ax = 0.f, ay = 0.f;
    if (c < n) {
      float dc = dinv[c];
      unsigned long long rb;
      if (MODE == 1) {
        const float* in = (const float*)inv;
        float2 v = ((const float2*)(in + (size_t)c * FDIM))[l];
        ax = dc * dc * v.x; ay = dc * dc * v.y;
        rb = (unsigned long long)(const char*)inv + ((size_t)l << 3);
      } else {
        const unsigned short* in = (const unsigned short*)inv;
        unsigned u = *(const unsigned*)(in + (size_t)c * FDIM + l * 2);
        ax = dc * dc * __uint_as_float(u << 16);
        ay = dc * dc * __uint_as_float(u & 0xFFFF0000u);
        rb = (unsigned long long)(const char*)inv + ((size_t)l << 2);
      }
      int st = rstart[c], cn = rstart[c + 1] - st;
      for (int q0 = 0; q0 < cn; q0 += 64) {
        int2 ep = (q0 + l < cn) ? pay[st + q0 + l] : make_int2(c, 0);
        int m = min(64, cn - q0);
        for (int g = 0; g < m; g += 8) {
          unsigned long long addr[8];
          float w[8];
#pragma unroll
          for (int u = 0; u < 8; u++) {
            int r = __shfl(ep.x, g + u, 64);
            w[u] = __int_as_float(__shfl(ep.y, g + u, 64));
            addr[u] = rb + ((unsigned long long)(unsigned)r << (MODE == 1 ? 9 : 8));
          }
          if (MODE == 1) {
            f32x2 ev[8];
#pragma unroll
            for (int u = 0; u < 8; u++)
              asm volatile("global_load_dwordx2 %0, %1, off" : "=v"(ev[u]) : "v"(addr[u]));
            asm volatile("s_waitcnt vmcnt(0)" ::: "memory");
            __builtin_amdgcn_sched_barrier(0);
#pragma unroll
            for (int u = 0; u < 8; u++) { ax += w[u] * ev[u][0]; ay += w[u] * ev[u][1]; }
          } else {
            unsigned uv[8];
#pragma unroll
            for (int u = 0; u < 8; u++)
              asm volatile("global_load_dword %0, %1, off" : "=v"(uv[u]) : "v"(addr[u]));
            asm volatile("s_waitcnt vmcnt(0)" ::: "memory");
            __builtin_amdgcn_sched_barrier(0);
#pragma unroll
            for (int u = 0; u < 8; u++) {
              ax += w[u] * __uint_as_float(uv[u] << 16);
              ay += w[u] * __uint_as_float(uv[u] & 0xFFFF0000u);
            }
          }
        }
      }
    }
    if (MODE == 2) {   // quantize to bf16 (round-half-up), keep as fp32 in LDS
      ax = __uint_as_float((__float_as_uint(ax) + 0x8000u) & 0xFFFF0000u);
      ay = __uint_as_float((__float_as_uint(ay) + 0x8000u) & 0xFFFF0000u);
    }
    gst[wv][i][2 * l]     = ax;
    gst[wv][i][2 * l + 1] = ay;
  }
  // wave-local LDS dependency only; compiler orders ds_write->ds_read.

  // ---- phase B: MFMA vs W + epilogue ----
  int lcol = l & 15, q = l >> 4;
  float pv[8];
#pragma unroll
  for (int ct = 0; ct < 8; ct++) pv[ct] = pvec[ct * 16 + lcol];
  float scale = scal[0];

  f32x4 acc[8];
#pragma unroll
  for (int c = 0; c < 8; c++) acc[c] = (f32x4){0.f, 0.f, 0.f, 0.f};

#pragma unroll
  for (int ks = 0; ks < 4; ks++) {
    const f32x4* gp = (const f32x4*)&gst[wv][lcol][q * 8 + ks * 32];
    f32x4 v0 = gp[0], v1 = gp[1];
    float xs[8] = {v0[0], v0[1], v0[2], v0[3], v1[0], v1[1], v1[2], v1[3]};
    bfrag ah, al;
#pragma unroll
    for (int i = 0; i < 8; i++) {
      unsigned u = __float_as_uint(xs[i]);
      ah[i] = (short)(u >> 16);
      if (MODE == 1) {
        float res = xs[i] - __uint_as_float(u & 0xFFFF0000u);
        al[i] = (short)(__float_as_uint(res) >> 16);
      }
    }
#pragma unroll
    for (int ct = 0; ct < 8; ct++) {
      size_t boff = (size_t)(ct * 16 + lcol) * FDIM + ks * 32 + q * 8;
      bfrag bh = *(const bfrag*)(BTh + boff);
      bfrag bl = *(const bfrag*)(BTl + boff);
      acc[ct] = __builtin_amdgcn_mfma_f32_16x16x32_bf16(ah, bh, acc[ct], 0, 0, 0);
      acc[ct] = __builtin_amdgcn_mfma_f32_16x16x32_bf16(ah, bl, acc[ct], 0, 0, 0);
      if (MODE == 1)
        acc[ct] = __builtin_amdgcn_mfma_f32_16x16x32_bf16(al, bh, acc[ct], 0, 0, 0);
    }
  }

  int rbase = base + q * 4;
  float part[4] = {0.f, 0.f, 0.f, 0.f};
#pragma unroll
  for (int ct = 0; ct < 8; ct++) {
    int col = ct * 16 + lcol;
#pragma unroll
    for (int r = 0; r < 4; r++) {
      int row = rbase + r;
      float rl = fmaxf(acc[ct][r], 0.0f);
      part[r] += rl * pv[ct];
      if (MODE == 1 && row < n) {
        unsigned u = __float_as_uint(rl);
        Y2[(size_t)row * FDIM + col] = (unsigned short)((u + 0x8000u) >> 16);
      }
    }
  }
#pragma unroll
  for (int r = 0; r < 4; r++) {
#pragma unroll
    for (int m = 1; m < 16; m <<= 1) part[r] += __shfl_xor(part[r], m, 64);
  }
  if (lcol == 0) {
#pragma unroll
    for (int r = 0; r < 4; r++) {
      int row = rbase + r;
      if (row < n) {
        if (MODE == 1) scOut[row] = part[r] * scale;
        else           scOut[row] = part[r] + scale;
      }
    }
  }
}

// ---------------------------------------------------------------------------

extern "C" void kernel_launch(void* const* d_in, const int* in_sizes, int n_in,
                              void* d_out, int out_size, void* d_ws, size_t ws_size,
                              hipStream_t stream) {
  const float* x    = (const float*)d_in[0];
  const int*   ei   = (const int*)d_in[1];
  const float* ew   = (const float*)d_in[2];
  const float* p1   = (const float*)d_in[3];
  const float* wih1 = (const float*)d_in[4];
  const float* whh1 = (const float*)d_in[5];
  const float* bih1 = (const float*)d_in[6];
  const float* bhh1 = (const float*)d_in[7];
  const float* h01  = (const float*)d_in[8];
  const float* p2   = (const float*)d_in[9];
  const float* wih2 = (const float*)d_in[10];
  const float* whh2 = (const float*)d_in[11];
  const float* bih2 = (const float*)d_in[12];
  const float* bhh2 = (const float*)d_in[13];
  const float* h02  = (const float*)d_in[14];
  const float* l1w  = (const float*)d_in[15];
  const float* l1b  = (const float*)d_in[16];
  const float* l2w  = (const float*)d_in[17];
  const float* l2b  = (const float*)d_in[18];
  float* out = (float*)d_out;

  const int N = in_sizes[0] / FDIM;
  const int E = in_sizes[2];

  // workspace layout
  size_t off = 0;
  auto alloc = [&](size_t bytes) -> char* {
    char* p = (char*)d_ws + off;
    off = (off + bytes + 255) & ~(size_t)255;
    return p;
  };
  // zero-init region (one memset): deg, cnt, csel1/2
  float* deg   = (float*)alloc((size_t)N * 4);
  int*   cnt   = (int*)alloc((size_t)N * 4);
  int*   csel1 = (int*)alloc(8);
  int*   csel2 = (int*)alloc(8);
  size_t zero_span = (size_t)((char*)(csel2 + 2) - (char*)deg);
  // rest
  float* sc2   = (float*)alloc((size_t)N * 4);      // layer-2 scores
  unsigned long long* candk = (unsigned long long*)alloc(4096 * 8);
  int*   tidx  = (int*)alloc(128 * 4);
  float* ttanh = (float*)alloc(128 * 4);
  float* invn1 = (float*)alloc(4);
  float* invn2 = (float*)alloc(4);
  float* thr1  = (float*)alloc(4);
  float* thr2  = (float*)alloc(4);
  float* samp  = (float*)alloc(2048 * 4);
  float* dinv  = (float*)alloc((size_t)N * 4);
  int*   rstart= (int*)alloc((size_t)(N + 1) * 4);
  int*   rnext = (int*)alloc((size_t)N * 4);
  const int nb = (N + 1023) / 1024;
  int*   bsum  = (int*)alloc((size_t)nb * 4);
  int2*  pay   = (int2*)alloc((size_t)E * 8);
  float* vvec  = (float*)alloc(128 * 4);
  float* cc    = (float*)alloc(4);
  unsigned short* WTh = (unsigned short*)alloc(128 * 128 * 2);
  unsigned short* WTl = (unsigned short*)alloc(128 * 128 * 2);
  unsigned short* h1 = (unsigned short*)alloc((size_t)N * FDIM * 2);  // bf16
  (void)ws_size; (void)n_in; (void)out_size;

  const int scoreblocks = (((N + 15) / 16 + 3) / 4 + 7) & ~7;   // mult of 8
  const int fggblocks   = ((N + 63) / 64 + 7) & ~7;             // 64 nodes/blk
  const int sampstride  = N / 2048;

  // ---- setup ----
  hipMemsetAsync(deg, 0, zero_span, stream);
  k_edge_deg<<<(E + 255) / 256, 256, 0, stream>>>(ei, ew, deg, cnt, E);
  k_scan1<<<nb, 256, 0, stream>>>(cnt, bsum, deg, dinv, N);
  k_scan2_setup<<<1, 128, 0, stream>>>(bsum, nb, rstart + N, p1, p2, invn1, invn2,
                                       l1w, l1b, l2w, l2b, vvec, cc);
  k_scan3<<<nb, 1024, 0, stream>>>(cnt, bsum, rstart, rnext, N);
  k_fill<<<(E + 255) / 256, 256, 0, stream>>>(ei, ew, dinv, rnext, pay, E);

  // ---- layer 1: topk(x) -> W1; h1 = relu((A~x) W1), sc2 fused ----
  k_sampdots<<<128, 256, 0, stream>>>(x, p1, invn1, samp, sampstride);
  k_thr16<0><<<32, 256, 0, stream>>>(samp, 1, thr1);
  k_scorecollect<<<scoreblocks, 256, 0, stream>>>(x, p1, invn1, thr1, candk, csel1, N);
  k_sel<<<1, 1024, 0, stream>>>(candk, csel1, tidx, ttanh);
  k_gru<0><<<128, 384, 0, stream>>>(x, tidx, ttanh, wih1, whh1, bih1, bhh1, h01, WTh, WTl);
  k_fgg<1><<<fggblocks, 256, 0, stream>>>(x, WTh, WTl, dinv, rstart, pay,
                                          h1, sc2, p2, invn2, N);

  // ---- layer 2: topk(sc2) -> W2; out = relu((A~h1) W2).v + cc ----
  k_thr16<1><<<32, 256, 0, stream>>>(sc2, sampstride, thr2);
  k_collect<<<(N + 255) / 256, 256, 0, stream>>>(sc2, thr2, candk, csel2, N);
  k_sel<<<1, 1024, 0, stream>>>(candk, csel2, tidx, ttanh);
  k_gru<1><<<128, 384, 0, stream>>>(h1, tidx, ttanh, wih2, whh2, bih2, bhh2, h02, WTh, WTl);
  k_fgg<2><<<fggblocks, 256, 0, stream>>>(h1, WTh, WTl, dinv, rstart, pay,
                                          nullptr, out, vvec, cc, N);
}

// Round 16
// 314.934 us; speedup vs baseline: 1.3754x; 1.3754x over previous
//
#include <hip/hip_runtime.h>
#include <cstdint>
#include <cstddef>

// ---------------------------------------------------------------------------
// TemporalGNN: 2x EvolveGCNH (TopK-pool -> GRU weight evolve -> GCNConv) + MLP
// N=100000 nodes, F=128, E=625000 edges, all fp32.
// R16: R13 structure (R15 fusion reverted). Dispatch-chain trims: local
//      invn/vvec/cc (deletes scan2_setup), edge_deg||sampdots and
//      scan1||thr16 merged, bsum-scan inlined into scan3. 18 -> 15 dispatches.
// ---------------------------------------------------------------------------

#define FDIM 128

typedef __attribute__((ext_vector_type(8))) short bfrag;   // 8 bf16 (4 VGPRs)
typedef __attribute__((ext_vector_type(4))) float f32x4;
typedef __attribute__((ext_vector_type(2))) float f32x2;

__device__ __forceinline__ float wave_sum(float v) {
#pragma unroll
  for (int m = 32; m >= 1; m >>= 1) v += __shfl_xor(v, m, 64);
  return v;
}

__device__ __forceinline__ float sigmoidf_(float x) {
  return 1.0f / (1.0f + expf(-x));
}

// monotone float->uint map (order-preserving)
__device__ __forceinline__ unsigned omap(float f) {
  unsigned u = __float_as_uint(f);
  return (u & 0x80000000u) ? ~u : (u | 0x80000000u);
}

// xcd-chunked block remap (requires gridDim.x % 8 == 0)
__device__ __forceinline__ int xcd_chunk(int b, int nb) {
  return (b & 7) * (nb >> 3) + (b >> 3);
}

// LDS byte swizzle for GEMM B tiles: row stride 256B, XOR col bits with row
__device__ __forceinline__ int swz(int row, int colb) {
  return row * 256 + (colb ^ ((row & 7) << 4));
}

// ---------------- D2: edge_deg (blocks < eb)  ||  sampdots (rest) -----------

__global__ __launch_bounds__(256) void k_edge_samp(
    const int* __restrict__ ei, const float* __restrict__ ew,
    float* deg, int* cnt, int E,
    const float* __restrict__ x, const float* __restrict__ p1,
    float* __restrict__ samp, int stride, int eb) {
  if ((int)blockIdx.x < eb) {
    int e = blockIdx.x * 256 + threadIdx.x;
    if (e < E) {
      int c = ei[E + e];
      atomicAdd(&deg[c], ew[e]);
      atomicAdd(&cnt[c], 1);
    }
  } else {
    int l = threadIdx.x & 63;
    int w = ((int)blockIdx.x - eb) * 4 + ((int)threadIdx.x >> 6);   // 0..511
    float2 pv = ((const float2*)p1)[l];
    float inv = 1.0f / sqrtf(wave_sum(pv.x * pv.x + pv.y * pv.y));
#pragma unroll
    for (int r = 0; r < 4; r++) {
      int si = w * 4 + r;
      float2 a = ((const float2*)(x + (size_t)(si * stride) * FDIM))[l];
      float s = wave_sum(a.x * pv.x + a.y * pv.y) * inv;
      if (l == 0) samp[si] = s;
    }
  }
}

// ---------------- D3: scan1 (blocks < nb)  ||  thr16 on samp (32 blocks) ----

__global__ __launch_bounds__(256) void k_scan1_thr(
    const int* __restrict__ cnt, int* bsum,
    const float* __restrict__ deg, float* __restrict__ dinv, int n, int nb,
    const float* __restrict__ samp, float* __restrict__ thr) {
  __shared__ float a[2048];                 // thr16 path (scan1 aliases front)
  int t = threadIdx.x;
  if ((int)blockIdx.x < nb) {
    int* s = (int*)a;                       // 256 ints
    int b = blockIdx.x;
    int base = b * 1024;
    int v = 0;
#pragma unroll
    for (int j = 0; j < 4; j++) {
      int i = base + j * 256 + t;
      if (i < n) { v += cnt[i]; dinv[i] = 1.0f / sqrtf(1.0f + deg[i]); }
    }
    s[t] = v; __syncthreads();
    for (int off = 128; off > 0; off >>= 1) {
      if (t < off) s[t] += s[t + off];
      __syncthreads();
    }
    if (t == 0) bsum[b] = s[0];
  } else {
    for (int i = t; i < 2048; i += 256) a[i] = samp[i];
    __syncthreads();
    int g = ((int)blockIdx.x - nb) * 256 + t;   // 0..8191
    int j = g >> 2, sub = g & 3;
    float v = a[j];
    int gt = 0, eq = 0;
    const float4* a4 = (const float4*)(a + sub * 512);
#pragma unroll 8
    for (int i = 0; i < 128; i++) {
      float4 b4 = a4[i];
      gt += (b4.x > v) + (b4.y > v) + (b4.z > v) + (b4.w > v);
      eq += (b4.x == v) + (b4.y == v) + (b4.z == v) + (b4.w == v);
    }
    gt += __shfl_xor(gt, 1, 64); eq += __shfl_xor(eq, 1, 64);
    gt += __shfl_xor(gt, 2, 64); eq += __shfl_xor(eq, 2, 64);
    if (sub == 0 && gt <= 15 && gt + eq > 15) thr[0] = v;
  }
}

// ---------------- D4: element scan with inlined bsum prefix -----------------

__global__ __launch_bounds__(1024) void k_scan23(const int* __restrict__ cnt,
                                                 const int* __restrict__ bsum,
                                                 int* rstart, int* rnext,
                                                 int n, int nb, int E_) {
  __shared__ int s[1024];
  __shared__ int bs[128];                  // nb <= 98 for this problem
  int b = blockIdx.x, t = threadIdx.x;
  if (t < nb) bs[t] = bsum[t];
  __syncthreads();
  if (t == 0) {
    int run = 0;
    for (int k = 0; k < nb; k++) { int v = bs[k]; bs[k] = run; run += v; }
  }
  __syncthreads();
  int base = bs[b];
  int i = b * 1024 + t;
  int v = (i < n) ? cnt[i] : 0;
  s[t] = v; __syncthreads();
  for (int off = 1; off < 1024; off <<= 1) {
    int tmp = (t >= off) ? s[t - off] : 0;
    __syncthreads();
    s[t] += tmp;
    __syncthreads();
  }
  if (i < n) { int ex = base + s[t] - v; rstart[i] = ex; rnext[i] = ex; }
  if (b == 0 && t == 0) rstart[n] = E_;
}

// scatter edge payload (row, norm) into CSR slots
__global__ void k_fill(const int* __restrict__ ei, const float* __restrict__ ew,
                       const float* __restrict__ dinv, int* rnext, int2* pay, int E) {
  int e = blockIdx.x * blockDim.x + threadIdx.x;
  if (e < E) {
    int r = ei[e];
    int c = ei[E + e];
    float nm = dinv[r] * ew[e] * dinv[c];
    int pos = atomicAdd(&rnext[c], 1);
    pay[pos] = make_int2(r, __float_as_int(nm));
  }
}

// ---------------- top-k helpers ----------------------------------------------

// 16th largest of 2048 strided sc samples (layer 2)
__global__ __launch_bounds__(256) void k_thr16s(const float* __restrict__ src, int stride,
                                                float* __restrict__ thr) {
  __shared__ float a[2048];
  int t = threadIdx.x;
  for (int i = t; i < 2048; i += 256) a[i] = src[(size_t)i * stride];
  __syncthreads();
  int g = blockIdx.x * 256 + t;
  int j = g >> 2, sub = g & 3;
  float v = a[j];
  int gt = 0, eq = 0;
  const float4* a4 = (const float4*)(a + sub * 512);
#pragma unroll 8
  for (int i = 0; i < 128; i++) {
    float4 b = a4[i];
    gt += (b.x > v) + (b.y > v) + (b.z > v) + (b.w > v);
    eq += (b.x == v) + (b.y == v) + (b.z == v) + (b.w == v);
  }
  gt += __shfl_xor(gt, 1, 64); eq += __shfl_xor(eq, 1, 64);
  gt += __shfl_xor(gt, 2, 64); eq += __shfl_xor(eq, 2, 64);
  if (sub == 0 && gt <= 15 && gt + eq > 15) thr[0] = v;
}

__global__ void k_collect(const float* __restrict__ sc, const float* __restrict__ thr,
                          unsigned long long* candk, int* csel, int n) {
  int i = blockIdx.x * blockDim.x + threadIdx.x;
  if (i >= n) return;
  float s = sc[i];
  if (s >= thr[0]) {
    int pos = atomicAdd(csel, 1);
    if (pos < 4096)
      candk[pos] = ((unsigned long long)omap(s) << 32) | (unsigned)(~(unsigned)i);
  }
}

// exact top-128 via rank counting (keys unique; 0ULL pads rank-neutral)
__global__ __launch_bounds__(1024) void k_sel(const unsigned long long* __restrict__ candk,
                                              const int* __restrict__ csel,
                                              int* tidx, float* ttanh) {
  __shared__ unsigned long long a[4104];
  int t = threadIdx.x;
  int nc = csel[0]; if (nc > 4096) nc = 4096;
  int ncp = (nc + 7) & ~7;
  for (int i = t; i < ncp; i += 1024) a[i] = (i < nc) ? candk[i] : 0ULL;
  __syncthreads();
  for (int j = t; j < nc; j += 1024) {
    unsigned long long key = a[j];
    int r = 0;
#pragma unroll 8
    for (int i = 0; i < ncp; i++) r += (a[i] > key);
    if (r < 128) {
      unsigned idx = ~(unsigned)key;
      unsigned hi = (unsigned)(key >> 32);
      unsigned u = (hi & 0x80000000u) ? (hi ^ 0x80000000u) : ~hi;
      tidx[r] = (int)idx;
      ttanh[r] = tanhf(__uint_as_float(u));
    }
  }
}

// ---------------- GRU weight evolve -> bf16-split transposed weights --------
// BF16IN=1: xin is bf16 (h1).

template <int BF16IN>
__global__ __launch_bounds__(384) void k_gru(const void* __restrict__ xinv,
                                             const int* __restrict__ tidx,
                                             const float* __restrict__ ttanh,
                                             const float* __restrict__ wih,
                                             const float* __restrict__ whh,
                                             const float* __restrict__ bih,
                                             const float* __restrict__ bhh,
                                             const float* __restrict__ h0,
                                             unsigned short* __restrict__ WT_hi,
                                             unsigned short* __restrict__ WT_lo) {
  __shared__ float xt[128], hs[128], gis[384], ghs[384];
  int r = blockIdx.x, t = threadIdx.x;
  if (t < 128) {
    int idx = tidx[r];
    float xv;
    if (BF16IN) {
      unsigned short u = ((const unsigned short*)xinv)[(size_t)idx * FDIM + t];
      xv = __uint_as_float((unsigned)u << 16);
    } else {
      xv = ((const float*)xinv)[(size_t)idx * FDIM + t];
    }
    xt[t] = xv * ttanh[r];
    hs[t] = h0[r * FDIM + t];
  }
  __syncthreads();
  float gi = bih[t], gh = bhh[t];
  const float4* wi4 = (const float4*)(wih + (size_t)t * FDIM);
  const float4* wh4 = (const float4*)(whh + (size_t)t * FDIM);
#pragma unroll 8
  for (int k = 0; k < 32; k++) {
    float4 av = wi4[k], bv = wh4[k];
    gi += av.x * xt[4 * k] + av.y * xt[4 * k + 1] + av.z * xt[4 * k + 2] + av.w * xt[4 * k + 3];
    gh += bv.x * hs[4 * k] + bv.y * hs[4 * k + 1] + bv.z * hs[4 * k + 2] + bv.w * hs[4 * k + 3];
  }
  gis[t] = gi; ghs[t] = gh;
  __syncthreads();
  if (t < 128) {
    float rg = sigmoidf_(gis[t] + ghs[t]);
    float zg = sigmoidf_(gis[t + 128] + ghs[t + 128]);
    float ng = tanhf(gis[t + 256] + rg * ghs[t + 256]);
    float w = (1.0f - zg) * ng + zg * hs[t];
    unsigned u = __float_as_uint(w);
    float res = w - __uint_as_float(u & 0xFFFF0000u);
    WT_hi[t * FDIM + r] = (unsigned short)(u >> 16);
    WT_lo[t * FDIM + r] = (unsigned short)(__float_as_uint(res) >> 16);
  }
}

// ---------------- GEMM via MFMA with LDS-staged B + fused epilogues ---------
// MODE=1: A=g1 fp32 (3-pass split) -> h1 bf16 + sc2[row] (invn2 local)
// MODE=2: A=g2 bf16 (2-pass)       -> out[row] = relu-dot(vvec)+cc (local)

template <int MODE>
__global__ __launch_bounds__(256) void k_gemm5(const float* __restrict__ Af,
                                               const unsigned short* __restrict__ Ab,
                                               const unsigned short* __restrict__ BTh,
                                               const unsigned short* __restrict__ BTl,
                                               unsigned short* __restrict__ Y2,
                                               float* __restrict__ scOut,
                                               const float* __restrict__ p2,
                                               const float* __restrict__ l1w,
                                               const float* __restrict__ l1b,
                                               const float* __restrict__ l2w,
                                               const float* __restrict__ l2b,
                                               int nrows) {
  __shared__ unsigned short sBh[128 * 128];   // 32 KB
  __shared__ unsigned short sBl[128 * 128];   // 32 KB
  int tid = threadIdx.x;
  int eb = xcd_chunk(blockIdx.x, gridDim.x);
  int rblk = eb * 128;
  if (rblk >= nrows) return;
  for (int i = tid; i < 2048; i += 256) {
    int row = i >> 4, colb = (i & 15) << 4;
    *(uint4*)((char*)sBh + swz(row, colb)) = ((const uint4*)BTh)[i];
    *(uint4*)((char*)sBl + swz(row, colb)) = ((const uint4*)BTl)[i];
  }
  __syncthreads();
  int wv = tid >> 6, l = tid & 63;
  int lcol = l & 15;
  int kgrp = (l >> 4) * 8;

  float pv[8];
  float scale;
  if (MODE == 1) {
#pragma unroll
    for (int ct = 0; ct < 8; ct++) pv[ct] = p2[ct * 16 + lcol];
    float lp = 0.f;
#pragma unroll
    for (int ct = 0; ct < 8; ct++) lp += pv[ct] * pv[ct];
#pragma unroll
    for (int m = 1; m < 16; m <<= 1) lp += __shfl_xor(lp, m, 64);
    scale = 1.0f / sqrtf(lp);            // invn2
  } else {
    float w0 = l2w[0], w1 = l2w[1];
#pragma unroll
    for (int ct = 0; ct < 8; ct++)
      pv[ct] = w0 * l1w[ct * 16 + lcol] + w1 * l1w[128 + ct * 16 + lcol];
    scale = w0 * l1b[0] + w1 * l1b[1] + l2b[0];   // cc
  }

  for (int tile = 0; tile < 2; tile++) {
    int r0 = rblk + wv * 32 + tile * 16;
    if (r0 >= nrows) break;
    int arow = min(r0 + lcol, nrows - 1);
    f32x4 acc[8];
#pragma unroll
    for (int c = 0; c < 8; c++) acc[c] = (f32x4){0.f, 0.f, 0.f, 0.f};
#pragma unroll
    for (int ks = 0; ks < 4; ks++) {
      bfrag ah, al;
      if (MODE == 1) {
        const float* xp = Af + (size_t)arow * FDIM + kgrp + ks * 32;
        float4 v0 = *(const float4*)(xp);
        float4 v1 = *(const float4*)(xp + 4);
        float xs[8] = {v0.x, v0.y, v0.z, v0.w, v1.x, v1.y, v1.z, v1.w};
#pragma unroll
        for (int i = 0; i < 8; i++) {
          unsigned u = __float_as_uint(xs[i]);
          float res = xs[i] - __uint_as_float(u & 0xFFFF0000u);
          ah[i] = (short)(u >> 16);
          al[i] = (short)(__float_as_uint(res) >> 16);
        }
      } else {
        ah = *(const bfrag*)(Ab + (size_t)arow * FDIM + kgrp + ks * 32);
      }
      int colb = (ks * 32 + kgrp) * 2;
#pragma unroll
      for (int ct = 0; ct < 8; ct++) {
        int off = swz(ct * 16 + lcol, colb);
        bfrag bh = *(const bfrag*)((const char*)sBh + off);
        bfrag bl = *(const bfrag*)((const char*)sBl + off);
        acc[ct] = __builtin_amdgcn_mfma_f32_16x16x32_bf16(ah, bh, acc[ct], 0, 0, 0);
        acc[ct] = __builtin_amdgcn_mfma_f32_16x16x32_bf16(ah, bl, acc[ct], 0, 0, 0);
        if (MODE == 1)
          acc[ct] = __builtin_amdgcn_mfma_f32_16x16x32_bf16(al, bh, acc[ct], 0, 0, 0);
      }
    }
    int rbase = r0 + (l >> 4) * 4;
    float part[4] = {0.f, 0.f, 0.f, 0.f};
#pragma unroll
    for (int ct = 0; ct < 8; ct++) {
      int col = ct * 16 + lcol;
#pragma unroll
      for (int r = 0; r < 4; r++) {
        int row = rbase + r;
        float rl = fmaxf(acc[ct][r], 0.0f);
        part[r] += rl * pv[ct];
        if (MODE == 1 && row < nrows) {
          unsigned u = __float_as_uint(rl);
          Y2[(size_t)row * FDIM + col] = (unsigned short)((u + 0x8000u) >> 16);
        }
      }
    }
#pragma unroll
    for (int r = 0; r < 4; r++) {
#pragma unroll
      for (int m = 1; m < 16; m <<= 1) part[r] += __shfl_xor(part[r], m, 64);
    }
    if (lcol == 0) {
#pragma unroll
      for (int r = 0; r < 4; r++) {
        int row = rbase + r;
        if (row < nrows) {
          if (MODE == 1) scOut[row] = part[r] * scale;
          else           scOut[row] = part[r] + scale;
        }
      }
    }
  }
}

// ---------------- GCN gather: 8-deep asm-pipelined edge loads ---------------
// L=1: in x fp32 (512B rows) -> g1 fp32; epi: score1 (invn local) + collect.
// L=2: in h1 bf16 (256B rows) -> g2 bf16; no epi.  XCD-chunked.

template <int L>
__global__ void k_gather5(const void* __restrict__ inv, void* __restrict__ outv,
                          const float* __restrict__ dinv,
                          const int* __restrict__ rstart,    // N+1
                          const int2* __restrict__ pay,
                          const float* __restrict__ p1,
                          const float* __restrict__ thr1,
                          unsigned long long* __restrict__ candk, int* __restrict__ csel,
                          int n) {
  int wv = threadIdx.x >> 6, l = threadIdx.x & 63;
  int eb = xcd_chunk(blockIdx.x, gridDim.x);
  int c = eb * 4 + wv;
  if (c >= n) return;
  float dc = dinv[c];
  float ax, ay, sx0, sx1;
  unsigned long long base;
  if (L == 1) {
    const float* in = (const float*)inv;
    float2 v = ((const float2*)(in + (size_t)c * FDIM))[l];
    sx0 = v.x; sx1 = v.y;
    ax = dc * dc * v.x; ay = dc * dc * v.y;
    base = (unsigned long long)(const char*)inv + ((size_t)l << 3);
  } else {
    const unsigned short* in = (const unsigned short*)inv;
    unsigned u = *(const unsigned*)(in + (size_t)c * FDIM + l * 2);
    sx0 = sx1 = 0.f;
    ax = dc * dc * __uint_as_float(u << 16);
    ay = dc * dc * __uint_as_float(u & 0xFFFF0000u);
    base = (unsigned long long)(const char*)inv + ((size_t)l << 2);
  }
  int st = rstart[c], cn = rstart[c + 1] - st;
  for (int q0 = 0; q0 < cn; q0 += 64) {
    int2 ep = (q0 + l < cn) ? pay[st + q0 + l] : make_int2(c, 0);
    int m = min(64, cn - q0);
    for (int g = 0; g < m; g += 8) {
      unsigned long long addr[8];
      float w[8];
#pragma unroll
      for (int u = 0; u < 8; u++) {
        int r = __shfl(ep.x, g + u, 64);
        w[u] = __int_as_float(__shfl(ep.y, g + u, 64));
        addr[u] = base + ((unsigned long long)(unsigned)r << (L == 1 ? 9 : 8));
      }
      if (L == 1) {
        f32x2 ev[8];
#pragma unroll
        for (int u = 0; u < 8; u++)
          asm volatile("global_load_dwordx2 %0, %1, off" : "=v"(ev[u]) : "v"(addr[u]));
        asm volatile("s_waitcnt vmcnt(0)" ::: "memory");
        __builtin_amdgcn_sched_barrier(0);
#pragma unroll
        for (int u = 0; u < 8; u++) { ax += w[u] * ev[u][0]; ay += w[u] * ev[u][1]; }
      } else {
        unsigned uv[8];
#pragma unroll
        for (int u = 0; u < 8; u++)
          asm volatile("global_load_dword %0, %1, off" : "=v"(uv[u]) : "v"(addr[u]));
        asm volatile("s_waitcnt vmcnt(0)" ::: "memory");
        __builtin_amdgcn_sched_barrier(0);
#pragma unroll
        for (int u = 0; u < 8; u++) {
          ax += w[u] * __uint_as_float(uv[u] << 16);
          ay += w[u] * __uint_as_float(uv[u] & 0xFFFF0000u);
        }
      }
    }
  }
  if (L == 1) {
    float* out = (float*)outv;
    ((float2*)(out + (size_t)c * FDIM))[l] = make_float2(ax, ay);
    // fused layer-1 score + collect (invn computed locally from p1)
    float2 pvv = ((const float2*)p1)[l];
    float inv1 = 1.0f / sqrtf(wave_sum(pvv.x * pvv.x + pvv.y * pvv.y));
    float s = wave_sum(sx0 * pvv.x + sx1 * pvv.y) * inv1;
    if (l == 0 && s >= thr1[0]) {
      int pos = atomicAdd(csel, 1);
      if (pos < 4096)
        candk[pos] = ((unsigned long long)omap(s) << 32) | (unsigned)(~(unsigned)c);
    }
  } else {
    unsigned* out = (unsigned*)outv;
    unsigned lo = (__float_as_uint(ax) + 0x8000u) >> 16;
    unsigned hi = (__float_as_uint(ay) + 0x8000u) >> 16;
    out[(size_t)c * (FDIM / 2) + l] = lo | (hi << 16);
  }
}

// ---------------------------------------------------------------------------

extern "C" void kernel_launch(void* const* d_in, const int* in_sizes, int n_in,
                              void* d_out, int out_size, void* d_ws, size_t ws_size,
                              hipStream_t stream) {
  const float* x    = (const float*)d_in[0];
  const int*   ei   = (const int*)d_in[1];
  const float* ew   = (const float*)d_in[2];
  const float* p1   = (const float*)d_in[3];
  const float* wih1 = (const float*)d_in[4];
  const float* whh1 = (const float*)d_in[5];
  const float* bih1 = (const float*)d_in[6];
  const float* bhh1 = (const float*)d_in[7];
  const float* h01  = (const float*)d_in[8];
  const float* p2   = (const float*)d_in[9];
  const float* wih2 = (const float*)d_in[10];
  const float* whh2 = (const float*)d_in[11];
  const float* bih2 = (const float*)d_in[12];
  const float* bhh2 = (const float*)d_in[13];
  const float* h02  = (const float*)d_in[14];
  const float* l1w  = (const float*)d_in[15];
  const float* l1b  = (const float*)d_in[16];
  const float* l2w  = (const float*)d_in[17];
  const float* l2b  = (const float*)d_in[18];
  float* out = (float*)d_out;

  const int N = in_sizes[0] / FDIM;
  const int E = in_sizes[2];

  // workspace layout
  size_t off = 0;
  auto alloc = [&](size_t bytes) -> char* {
    char* p = (char*)d_ws + off;
    off = (off + bytes + 255) & ~(size_t)255;
    return p;
  };
  // zero-init region (one memset): deg, cnt, csel1/2
  float* deg   = (float*)alloc((size_t)N * 4);
  int*   cnt   = (int*)alloc((size_t)N * 4);
  int*   csel1 = (int*)alloc(8);
  int*   csel2 = (int*)alloc(8);
  size_t zero_span = (size_t)((char*)(csel2 + 2) - (char*)deg);
  // rest
  float* sc2   = (float*)alloc((size_t)N * 4);      // layer-2 scores
  unsigned long long* candk = (unsigned long long*)alloc(4096 * 8);
  int*   tidx  = (int*)alloc(128 * 4);
  float* ttanh = (float*)alloc(128 * 4);
  float* thr1  = (float*)alloc(4);
  float* thr2  = (float*)alloc(4);
  float* samp  = (float*)alloc(2048 * 4);
  float* dinv  = (float*)alloc((size_t)N * 4);
  int*   rstart= (int*)alloc((size_t)(N + 1) * 4);
  int*   rnext = (int*)alloc((size_t)N * 4);
  const int nb = (N + 1023) / 1024;                 // 98 (<=128 assumed)
  int*   bsum  = (int*)alloc((size_t)nb * 4);
  int2*  pay   = (int2*)alloc((size_t)E * 8);
  unsigned short* WTh = (unsigned short*)alloc(128 * 128 * 2);
  unsigned short* WTl = (unsigned short*)alloc(128 * 128 * 2);
  float* g1    = (float*)alloc((size_t)N * FDIM * 4);                // A~x fp32
  unsigned short* h1 = (unsigned short*)alloc((size_t)N * FDIM * 2); // bf16
  unsigned short* g2 = (unsigned short*)alloc((size_t)N * FDIM * 2); // bf16
  (void)ws_size; (void)n_in; (void)out_size;

  const int edgeblocks  = (E + 255) / 256;
  const int gemmblocks  = ((N + 127) / 128 + 7) & ~7;           // 128 rows/blk
  const int gatherblocks= (N + 3) / 4;                          // %8 == 0
  const int sampstride  = N / 2048;

  // ---- D1..D5: setup (CSR) with layer-1 sampling overlapped ----
  hipMemsetAsync(deg, 0, zero_span, stream);
  k_edge_samp<<<edgeblocks + 128, 256, 0, stream>>>(ei, ew, deg, cnt, E,
                                                    x, p1, samp, sampstride, edgeblocks);
  k_scan1_thr<<<nb + 32, 256, 0, stream>>>(cnt, bsum, deg, dinv, N, nb, samp, thr1);
  k_scan23<<<nb, 1024, 0, stream>>>(cnt, bsum, rstart, rnext, N, nb, E);
  k_fill<<<edgeblocks, 256, 0, stream>>>(ei, ew, dinv, rnext, pay, E);

  // ---- layer 1: g1 = A~x (fused score1+collect), W1, h1 = relu(g1 W1) ----
  k_gather5<1><<<gatherblocks, 256, 0, stream>>>(x, g1, dinv, rstart, pay,
                                                 p1, thr1, candk, csel1, N);
  k_sel<<<1, 1024, 0, stream>>>(candk, csel1, tidx, ttanh);
  k_gru<0><<<128, 384, 0, stream>>>(x, tidx, ttanh, wih1, whh1, bih1, bhh1, h01, WTh, WTl);
  k_gemm5<1><<<gemmblocks, 256, 0, stream>>>(g1, nullptr, WTh, WTl, h1, sc2,
                                             p2, l1w, l1b, l2w, l2b, N);

  // ---- layer 2: top-k on sc2, W2, g2 = A~h1, out = relu(g2 W2).v + cc ----
  k_thr16s<<<32, 256, 0, stream>>>(sc2, sampstride, thr2);
  k_collect<<<(N + 255) / 256, 256, 0, stream>>>(sc2, thr2, candk, csel2, N);
  k_sel<<<1, 1024, 0, stream>>>(candk, csel2, tidx, ttanh);
  k_gru<1><<<128, 384, 0, stream>>>(h1, tidx, ttanh, wih2, whh2, bih2, bhh2, h02, WTh, WTl);
  k_gather5<2><<<gatherblocks, 256, 0, stream>>>(h1, g2, dinv, rstart, pay,
                                                 nullptr, nullptr, nullptr, nullptr, N);
  k_gemm5<2><<<gemmblocks, 256, 0, stream>>>(nullptr, g2, WTh, WTl, nullptr, out,
                                             p2, l1w, l1b, l2w, l2b, N);
}